// Round 2
// baseline (135.033 us; speedup 1.0000x reference)
//
#include <hip/hip_runtime.h>
#include <math.h>

#define J 5

#if defined(__HIP_DEVICE_COMPILE__) && __has_builtin(__builtin_amdgcn_rcpf)
__device__ __forceinline__ float fastrcp(float x) { return __builtin_amdgcn_rcpf(x); }
#else
__device__ __forceinline__ float fastrcp(float x) { return 1.0f / x; }
#endif

#if defined(__HIP_DEVICE_COMPILE__) && __has_builtin(__builtin_amdgcn_rsqf)
__device__ __forceinline__ float fastrsq(float x) { return __builtin_amdgcn_rsqf(x); }
#else
__device__ __forceinline__ float fastrsq(float x) { return 1.0f / sqrtf(x); }
#endif

// Derived-constant layout in d_ws (floats):
//  [0..4]   ewl   = exp(w_logm)
//  [5..9]   bl    = b_logm
//  [10..14] ewl2  = ewl^2
//  [15..19] newt  = -exp(w_ttm)
//  [20..24] nbt   = -b_ttm
//  [25..29] ewe   = exp(w_exp)
//  [30..34] wte   = exp(w_ttm)*exp(w_exp)
//  [35..39] r1_i  = sum_j W1[i,j]
//  [40..44] c1_i  = b1_i + sum_j W1[i,j]*b_exp_j
//  [45..49] r1sq  = r1^2
//  [50..74] W2
//  [75..79] b2
//  [80..84] Wo
//  [85]     bo
__global__ void setup_kernel(const float* __restrict__ w_logm, const float* __restrict__ b_logm,
                             const float* __restrict__ w_ttm,  const float* __restrict__ b_ttm,
                             const float* __restrict__ w_exp,  const float* __restrict__ b_exp,
                             const float* __restrict__ W1,     const float* __restrict__ b1,
                             const float* __restrict__ W2,     const float* __restrict__ b2,
                             const float* __restrict__ Wo,     const float* __restrict__ bo,
                             float* __restrict__ c)
{
    const int j = threadIdx.x;
    if (j >= J) return;
    const float ewl = __expf(w_logm[j]);
    const float ewt = __expf(w_ttm[j]);
    const float ewe = __expf(w_exp[j]);
    c[0  + j] = ewl;
    c[5  + j] = b_logm[j];
    c[10 + j] = ewl * ewl;
    c[15 + j] = -ewt;
    c[20 + j] = -b_ttm[j];
    c[25 + j] = ewe;
    c[30 + j] = ewt * ewe;
    float r = 0.0f, cc = b1[j];
#pragma unroll
    for (int t = 0; t < J; ++t) {
        const float w = W1[j * J + t];
        r += w;
        cc = fmaf(w, b_exp[t], cc);
    }
    c[35 + j] = r;
    c[40 + j] = cc;
    c[45 + j] = r * r;
#pragma unroll
    for (int t = 0; t < J; ++t) c[50 + j * J + t] = W2[j * J + t];
    c[75 + j] = b2[j];
    c[80 + j] = Wo[j];
    if (j == 0) c[85] = bo[0];
}

// softplus + sigmoid, overflow-safe: sp = max(a,0)+log1p(e^-|a|), sg from same exp
__device__ __forceinline__ void softplus_sig(float a, float& sp, float& sg) {
    const float aa = fabsf(a);
    const float em = __expf(-aa);
    const float w  = fastrcp(1.0f + em);        // sigmoid(|a|)
    sp = fmaxf(a, 0.0f) + __logf(1.0f + em);
    sg = (a >= 0.0f) ? w : 1.0f - w;
}

__global__ __launch_bounds__(256) void smile_main(
    const float* __restrict__ ttm, const float* __restrict__ logm,
    const float* __restrict__ c, float* __restrict__ out, int n)
{
    const int tid = blockIdx.x * blockDim.x + threadIdx.x;
    if (tid * 4 >= n) return;

    // ---- uniform read-only loads -> SGPRs (no per-thread VALU on params) ----
    float ewl[J], bl[J], ewl2[J], newt[J], nbt[J], ewe[J], wte[J];
#pragma unroll
    for (int j = 0; j < J; ++j) {
        ewl[j]  = c[0  + j];
        bl[j]   = c[5  + j];
        ewl2[j] = c[10 + j];
        newt[j] = c[15 + j];
        nbt[j]  = c[20 + j];
        ewe[j]  = c[25 + j];
        wte[j]  = c[30 + j];
    }

    const float4 T4 = ((const float4*)ttm)[tid];
    const float4 L4 = ((const float4*)logm)[tid];
    const float Ts[4] = {T4.x, T4.y, T4.z, T4.w};
    const float Ls[4] = {L4.x, L4.y, L4.z, L4.w};

    // ================= phase 1: smile layer (all 4 samples) =================
    float sA[4], sLA[4], sLLA[4], sTA[4];
#pragma unroll
    for (int k = 0; k < 4; ++k) {
        const float L = Ls[k], T = Ts[k];
        float s = 0.0f, sL = 0.0f, sLL = 0.0f, sT = 0.0f;
#pragma unroll
        for (int j = 0; j < J; ++j) {
            float x = fmaf(L, ewl[j], bl[j]);
            x = fminf(fmaxf(x, -30.0f), 30.0f);          // overflow guard (v_med3)
            const float ex = __expf(x);
            const float e2 = ex * ex;
            // tanh(x+0.5) = 1 - 2/(e*ex^2 + 1)
            const float t1 = fmaf(-2.0f, fastrcp(fmaf(2.7182818284590452f, e2, 1.0f)), 1.0f);
            // tanh(-x/2) = (1-ex)/(1+ex)
            const float t2 = (1.0f - ex) * fastrcp(1.0f + ex);
            const float m1 = fmaf(-t1, t1, 1.0f);        // sech^2(x+0.5)
            const float m2 = fmaf(-t2, t2, 1.0f);        // sech^2(x/2)
            const float u  = fmaf(x, t1, t2 + 5.0e-4f);
            const float xm1 = x * m1;
            const float ux  = fmaf(-0.5f, m2, t1 + xm1);
            const float uxx = fmaf(-0.5f * t2, m2, 2.0f * fmaf(-t1, xm1, m1));
            const float r   = fastrsq(u);                // 1/sqrt(u)
            const float tl  = u * r;                     // sqrt(u)
            const float i2  = 0.5f * r;                  // 1/(2 sqrt u)
            const float h   = ux * (r * r);              // ux/u
            // sigmoid(bt + T*ewt) via zn = -(bt+T*ewt)
            const float zn  = fmaf(T, newt[j], nbt[j]);
            const float tt  = fastrcp(1.0f + __expf(zn));
            const float dtt = fmaf(-tt, tt, tt);
            const float AA   = tt * ewe[j];
            const float ewlA = ewl[j] * AA;
            s   = fmaf(tl, AA, s);
            sL  = fmaf(ux * i2, ewlA, sL);
            const float inner = fmaf(-0.5f * ux, h, uxx); // uxx - ux^2/(2u)
            sLL = fmaf(inner * i2, ewl[j] * ewlA, sLL);   // * ewl2 * AA
            sT  = fmaf(tl * dtt, wte[j], sT);
            (void)ewl2;
        }
        sA[k] = s; sLA[k] = sL; sLLA[k] = sLL; sTA[k] = sT;
    }

    // ================= phase 2: MLP layers (all 4 samples) =================
    float r1[J], c1[J], r1sq[J], W2r[J * J], b2[J], wo[J];
#pragma unroll
    for (int j = 0; j < J; ++j) {
        r1[j]   = c[35 + j];
        c1[j]   = c[40 + j];
        r1sq[j] = c[45 + j];
        b2[j]   = c[75 + j];
        wo[j]   = c[80 + j];
    }
#pragma unroll
    for (int t = 0; t < J * J; ++t) W2r[t] = c[50 + t];
    const float bo0 = c[85];

    float O0[4], O1[4], O2[4], O3[4];
#pragma unroll
    for (int k = 0; k < 4; ++k) {
        const float s = sA[k], sL = sLA[k], sLL = sLLA[k], sT = sTA[k];

        // layer 1 (folded affine): a_i = s*r1_i + c1_i
        float q[J], p[J], sp1[J];
#pragma unroll
        for (int i = 0; i < J; ++i) {
            const float a = fmaf(s, r1[i], c1[i]);
            float sp, sg;
            softplus_sig(a, sp, sg);
            sp1[i] = sp;
            q[i]   = sg * r1[i];                    // h1L = sL*q, h1T = sT*q
            const float dsg = fmaf(-sg, sg, sg);
            p[i]   = dsg * r1sq[i];                 // h1LL = sL^2*p + sLL*q
        }

        // layer 2 + head, scalars factored out:
        //  gL = sL*Bq, gT = sT*Bq, gLL = sL^2*Bp + sLL*Bq
        float o = bo0, u1 = 0.0f, u2 = 0.0f, u3 = 0.0f;
#pragma unroll
        for (int i = 0; i < J; ++i) {
            float g = b2[i], Bq = 0.0f, Bp = 0.0f;
#pragma unroll
            for (int j = 0; j < J; ++j) {
                const float w = W2r[i * J + j];
                g  = fmaf(w, sp1[j], g);
                Bq = fmaf(w, q[j],   Bq);
                Bp = fmaf(w, p[j],   Bp);
            }
            float sp, sg;
            softplus_sig(g, sp, sg);
            const float dsg = fmaf(-sg, sg, sg);
            const float t   = wo[i] * sg;
            o  = fmaf(wo[i], sp, o);
            u1 = fmaf(t, Bq, u1);
            u2 = fmaf(t, Bp, u2);
            u3 = fmaf(wo[i] * dsg, Bq * Bq, u3);
        }
        O0[k] = o;
        O1[k] = sT * u1;                             // d/dttm
        O2[k] = sL * u1;                             // d/dlogm
        O3[k] = fmaf(sL * sL, u3 + u2, sLL * u1);    // d2/dlogm2
    }

    ((float4*)(out))[tid]                 = make_float4(O0[0], O0[1], O0[2], O0[3]);
    ((float4*)(out + (size_t)n))[tid]     = make_float4(O1[0], O1[1], O1[2], O1[3]);
    ((float4*)(out + 2 * (size_t)n))[tid] = make_float4(O2[0], O2[1], O2[2], O2[3]);
    ((float4*)(out + 3 * (size_t)n))[tid] = make_float4(O3[0], O3[1], O3[2], O3[3]);
}

extern "C" void kernel_launch(void* const* d_in, const int* in_sizes, int n_in,
                              void* d_out, int out_size, void* d_ws, size_t ws_size,
                              hipStream_t stream) {
    const float* ttm    = (const float*)d_in[0];
    const float* logm   = (const float*)d_in[1];
    const float* w_logm = (const float*)d_in[2];
    const float* b_logm = (const float*)d_in[3];
    const float* w_ttm  = (const float*)d_in[4];
    const float* b_ttm  = (const float*)d_in[5];
    const float* w_exp  = (const float*)d_in[6];
    const float* b_exp  = (const float*)d_in[7];
    const float* W1     = (const float*)d_in[8];
    const float* b1     = (const float*)d_in[9];
    const float* W2     = (const float*)d_in[10];
    const float* b2     = (const float*)d_in[11];
    const float* Wo     = (const float*)d_in[12];
    const float* bo     = (const float*)d_in[13];
    float* out = (float*)d_out;
    float* cns = (float*)d_ws;

    const int n = in_sizes[0];
    setup_kernel<<<1, 64, 0, stream>>>(w_logm, b_logm, w_ttm, b_ttm, w_exp, b_exp,
                                       W1, b1, W2, b2, Wo, bo, cns);
    const int threads = (n + 3) / 4;
    const int blocks  = (threads + 255) / 256;
    smile_main<<<blocks, 256, 0, stream>>>(ttm, logm, cns, out, n);
}

// Round 3
// 121.725 us; speedup vs baseline: 1.1093x; 1.1093x over previous
//
#include <hip/hip_runtime.h>
#include <math.h>

#define J 5
#define LOG2E 1.4426950408889634f
#define LN2   0.6931471805599453f

#if defined(__HIP_DEVICE_COMPILE__) && __has_builtin(__builtin_amdgcn_rcpf)
__device__ __forceinline__ float fastrcp(float x) { return __builtin_amdgcn_rcpf(x); }
#else
__device__ __forceinline__ float fastrcp(float x) { return 1.0f / x; }
#endif

#if defined(__HIP_DEVICE_COMPILE__) && __has_builtin(__builtin_amdgcn_rsqf)
__device__ __forceinline__ float fastrsq(float x) { return __builtin_amdgcn_rsqf(x); }
#else
__device__ __forceinline__ float fastrsq(float x) { return 1.0f / sqrtf(x); }
#endif

// v_exp_f32 / v_log_f32 are base-2. Keep everything in log2 domain.
#if defined(__HIP_DEVICE_COMPILE__) && __has_builtin(__builtin_amdgcn_exp2f)
__device__ __forceinline__ float fexp2(float x) { return __builtin_amdgcn_exp2f(x); }
#else
__device__ __forceinline__ float fexp2(float x) { return exp2f(x); }
#endif

#if defined(__HIP_DEVICE_COMPILE__) && __has_builtin(__builtin_amdgcn_logf)
__device__ __forceinline__ float flog2(float x) { return __builtin_amdgcn_logf(x); }
#else
__device__ __forceinline__ float flog2(float x) { return log2f(x); }
#endif

// d_ws derived-constant layout (floats):
//  [0..4]   ewlb  = exp(w_logm)*LOG2E      (x2 = L*ewlb + blb; e^x = 2^x2)
//  [5..9]   blb   = b_logm*LOG2E
//  [10..14] ewl   = exp(w_logm)            (true dx/dL, for derivative chain)
//  [15..19] newtb = -exp(w_ttm)*LOG2E      (sigmoid arg in log2 domain)
//  [20..24] nbtb  = -b_ttm*LOG2E
//  [25..29] ewe   = exp(w_exp)
//  [30..34] wte   = exp(w_ttm)*exp(w_exp)
//  [35..39] r1    = sum_j W1[i,j]                    (true)
//  [40..44] r1b   = r1*LOG2E
//  [45..49] c1b   = (b1 + W1@b_exp)*LOG2E
//  [50..54] r1sq  = r1^2
//  [55..79] W2    (unmodified: ln2*log2e = 1 folds through softplus chain)
//  [80..84] b2b   = b2*LOG2E
//  [85..89] wo    (true, for derivative track)
//  [90..94] wob   = wo*LN2  (value track: o = sum wob*log2(1+2^g2) + bo)
//  [95]     bo
__global__ void setup_kernel(const float* __restrict__ w_logm, const float* __restrict__ b_logm,
                             const float* __restrict__ w_ttm,  const float* __restrict__ b_ttm,
                             const float* __restrict__ w_exp,  const float* __restrict__ b_exp,
                             const float* __restrict__ W1,     const float* __restrict__ b1,
                             const float* __restrict__ W2,     const float* __restrict__ b2,
                             const float* __restrict__ Wo,     const float* __restrict__ bo,
                             float* __restrict__ c)
{
    const int j = threadIdx.x;
    if (j >= J) return;
    const float ewl = __expf(w_logm[j]);
    const float ewt = __expf(w_ttm[j]);
    const float ewe = __expf(w_exp[j]);
    c[0  + j] = ewl * LOG2E;
    c[5  + j] = b_logm[j] * LOG2E;
    c[10 + j] = ewl;
    c[15 + j] = -ewt * LOG2E;
    c[20 + j] = -b_ttm[j] * LOG2E;
    c[25 + j] = ewe;
    c[30 + j] = ewt * ewe;
    float r = 0.0f, cc = b1[j];
#pragma unroll
    for (int t = 0; t < J; ++t) {
        const float w = W1[j * J + t];
        r += w;
        cc = fmaf(w, b_exp[t], cc);
    }
    c[35 + j] = r;
    c[40 + j] = r * LOG2E;
    c[45 + j] = cc * LOG2E;
    c[50 + j] = r * r;
#pragma unroll
    for (int t = 0; t < J; ++t) c[55 + j * J + t] = W2[j * J + t];
    c[80 + j] = b2[j] * LOG2E;
    c[85 + j] = Wo[j];
    c[90 + j] = Wo[j] * LN2;
    if (j == 0) c[95] = bo[0];
}

__global__ __launch_bounds__(256, 6) void smile_main(
    const float* __restrict__ ttm, const float* __restrict__ logm,
    const float* __restrict__ c, float* __restrict__ out, int n)
{
    const int tid = blockIdx.x * blockDim.x + threadIdx.x;
    if (tid >= n) return;

    const float T = ttm[tid];
    const float L = logm[tid];

    // ---- uniform loads -> s_load / SGPRs ----
    float ewlb[J], blb[J], ewl[J], newtb[J], nbtb[J], ewe[J], wte[J];
#pragma unroll
    for (int j = 0; j < J; ++j) {
        ewlb[j]  = c[0  + j];
        blb[j]   = c[5  + j];
        ewl[j]   = c[10 + j];
        newtb[j] = c[15 + j];
        nbtb[j]  = c[20 + j];
        ewe[j]   = c[25 + j];
        wte[j]   = c[30 + j];
    }

    // ============ phase 1: smile layer + d/dL, d2/dL2, d/dT ============
    float s = 0.0f, sL = 0.0f, sLL = 0.0f, sT = 0.0f;
#pragma unroll
    for (int j = 0; j < J; ++j) {
        const float x2 = fmaf(L, ewlb[j], blb[j]);   // x*log2(e)
        const float ex = fexp2(x2);                  // e^x
        const float x  = x2 * LN2;
        const float e2 = ex * ex;
        // tanh(x+0.5) = 1 - 2/(e*e^{2x}+1)
        const float w1 = fastrcp(fmaf(2.7182818284590452f, e2, 1.0f));
        const float t1 = fmaf(-2.0f, w1, 1.0f);
        // tanh(-x/2) = 2/(1+e^x) - 1
        const float w2 = fastrcp(1.0f + ex);
        const float t2 = fmaf(2.0f, w2, -1.0f);
        const float m1 = fmaf(-t1, t1, 1.0f);        // sech^2(x+0.5)
        const float m2 = fmaf(-t2, t2, 1.0f);        // sech^2(x/2)
        const float u  = fmaf(x, t1, t2 + 5.0e-4f);
        const float xm1 = x * m1;
        const float ux  = fmaf(-0.5f, m2, t1 + xm1);
        const float f1  = fmaf(-t1, xm1, m1);
        const float uxx = fmaf(-0.5f * t2, m2, f1 + f1);
        const float r   = fastrsq(u);                // u^{-1/2}
        const float tl  = u * r;                     // sqrt(u)
        const float i2  = 0.5f * r;
        const float h   = ux * (r * r);              // ux/u
        // sigmoid(b_ttm + T*exp(w_ttm)) via 2^{-(arg)*log2e}
        const float tt  = fastrcp(1.0f + fexp2(fmaf(T, newtb[j], nbtb[j])));
        const float dtt = fmaf(-tt, tt, tt);
        const float AA   = tt * ewe[j];
        const float ewlA = ewl[j] * AA;
        s  = fmaf(tl, AA, s);
        const float G = ux * i2;                     // d sqrt(u)/dx
        sL = fmaf(G, ewlA, sL);
        const float inner = fmaf(-0.5f * ux, h, uxx); // uxx - ux^2/(2u)
        sLL = fmaf(inner * i2, ewl[j] * ewlA, sLL);
        sT  = fmaf(tl * dtt, wte[j], sT);
    }

    // ============ phase 2: MLP (log2-domain softplus chain) ============
    float r1[J], r1b[J], c1b[J], r1sq[J], W2r[J * J], b2b[J], wo[J], wob[J];
#pragma unroll
    for (int j = 0; j < J; ++j) {
        r1[j]   = c[35 + j];
        r1b[j]  = c[40 + j];
        c1b[j]  = c[45 + j];
        r1sq[j] = c[50 + j];
        b2b[j]  = c[80 + j];
        wo[j]   = c[85 + j];
        wob[j]  = c[90 + j];
    }
#pragma unroll
    for (int t = 0; t < J * J; ++t) W2r[t] = c[55 + t];
    const float bo0 = c[95];

    // layer 1: a2_i = s*r1b_i + c1b_i  (= a_true*log2e)
    float sp2[J], q[J], p[J];
#pragma unroll
    for (int i = 0; i < J; ++i) {
        const float a2 = fmaf(s, r1b[i], c1b[i]);
        const float ex = fexp2(a2);                  // e^{a_true}
        const float d  = 1.0f + ex;
        const float w  = fastrcp(d);
        const float sg = 1.0f - w;                   // true sigmoid
        sp2[i] = flog2(d);                           // softplus/ln2
        q[i]   = sg * r1[i];
        p[i]   = (w * sg) * r1sq[i];                 // dsg * r1^2
    }

    // layer 2 + head: g2 = W2@sp2 + b2b  (= g_true*log2e); Bq,Bp true-domain
    float o = bo0, u1 = 0.0f, u2 = 0.0f, u3 = 0.0f;
#pragma unroll
    for (int i = 0; i < J; ++i) {
        float g2 = b2b[i], Bq = 0.0f, Bp = 0.0f;
#pragma unroll
        for (int j = 0; j < J; ++j) {
            const float w = W2r[i * J + j];
            g2 = fmaf(w, sp2[j], g2);
            Bq = fmaf(w, q[j],   Bq);
            Bp = fmaf(w, p[j],   Bp);
        }
        const float ex = fexp2(g2);                  // e^{g_true}
        const float d  = 1.0f + ex;
        const float w  = fastrcp(d);
        const float sg = 1.0f - w;
        const float dsg = w * sg;
        o  = fmaf(wob[i], flog2(d), o);              // wo*softplus
        const float t = wo[i] * sg;
        u1 = fmaf(t, Bq, u1);
        u2 = fmaf(t, Bp, u2);
        u3 = fmaf(wo[i] * dsg, Bq * Bq, u3);
    }

    const size_t nn = (size_t)n;
    out[tid]          = o;                               // output
    out[nn + tid]     = sT * u1;                         // grad_ttm1
    out[2 * nn + tid] = sL * u1;                         // grad_logm1
    out[3 * nn + tid] = fmaf(sL * sL, u3 + u2, sLL * u1); // grad_logm2
}

extern "C" void kernel_launch(void* const* d_in, const int* in_sizes, int n_in,
                              void* d_out, int out_size, void* d_ws, size_t ws_size,
                              hipStream_t stream) {
    const float* ttm    = (const float*)d_in[0];
    const float* logm   = (const float*)d_in[1];
    const float* w_logm = (const float*)d_in[2];
    const float* b_logm = (const float*)d_in[3];
    const float* w_ttm  = (const float*)d_in[4];
    const float* b_ttm  = (const float*)d_in[5];
    const float* w_exp  = (const float*)d_in[6];
    const float* b_exp  = (const float*)d_in[7];
    const float* W1     = (const float*)d_in[8];
    const float* b1     = (const float*)d_in[9];
    const float* W2     = (const float*)d_in[10];
    const float* b2     = (const float*)d_in[11];
    const float* Wo     = (const float*)d_in[12];
    const float* bo     = (const float*)d_in[13];
    float* out = (float*)d_out;
    float* cns = (float*)d_ws;

    const int n = in_sizes[0];
    setup_kernel<<<1, 64, 0, stream>>>(w_logm, b_logm, w_ttm, b_ttm, w_exp, b_exp,
                                       W1, b1, W2, b2, Wo, bo, cns);
    const int blocks = (n + 255) / 256;
    smile_main<<<blocks, 256, 0, stream>>>(ttm, logm, cns, out, n);
}

// Round 4
// 112.302 us; speedup vs baseline: 1.2024x; 1.0839x over previous
//
#include <hip/hip_runtime.h>
#include <math.h>

#define J 5
#define LOG2E 1.4426950408889634f
#define LN2   0.6931471805599453f

typedef float v2f __attribute__((ext_vector_type(2)));

#if defined(__HIP_DEVICE_COMPILE__) && __has_builtin(__builtin_amdgcn_rcpf)
__device__ __forceinline__ float fastrcp(float x) { return __builtin_amdgcn_rcpf(x); }
#else
__device__ __forceinline__ float fastrcp(float x) { return 1.0f / x; }
#endif

#if defined(__HIP_DEVICE_COMPILE__) && __has_builtin(__builtin_amdgcn_rsqf)
__device__ __forceinline__ float fastrsq(float x) { return __builtin_amdgcn_rsqf(x); }
#else
__device__ __forceinline__ float fastrsq(float x) { return 1.0f / sqrtf(x); }
#endif

#if defined(__HIP_DEVICE_COMPILE__) && __has_builtin(__builtin_amdgcn_exp2f)
__device__ __forceinline__ float fexp2(float x) { return __builtin_amdgcn_exp2f(x); }
#else
__device__ __forceinline__ float fexp2(float x) { return exp2f(x); }
#endif

#if defined(__HIP_DEVICE_COMPILE__) && __has_builtin(__builtin_amdgcn_logf)
__device__ __forceinline__ float flog2(float x) { return __builtin_amdgcn_logf(x); }
#else
__device__ __forceinline__ float flog2(float x) { return log2f(x); }
#endif

// ---- packed helpers: <2 x float> ops lower to v_pk_{fma,mul,add}_f32 ----
__device__ __forceinline__ v2f v2s(float a) { return (v2f){a, a}; }
__device__ __forceinline__ v2f vfma(v2f a, v2f b, v2f c) { return __builtin_elementwise_fma(a, b, c); }
__device__ __forceinline__ v2f vfma(v2f a, float b, v2f c) { return __builtin_elementwise_fma(a, v2s(b), c); }
__device__ __forceinline__ v2f vfma(v2f a, float b, float c) { return __builtin_elementwise_fma(a, v2s(b), v2s(c)); }
// transcendentals have no packed form — scalarize per component
__device__ __forceinline__ v2f v2exp2(v2f x) { return (v2f){fexp2(x.x), fexp2(x.y)}; }
__device__ __forceinline__ v2f v2rcp (v2f x) { return (v2f){fastrcp(x.x), fastrcp(x.y)}; }
__device__ __forceinline__ v2f v2rsq (v2f x) { return (v2f){fastrsq(x.x), fastrsq(x.y)}; }
__device__ __forceinline__ v2f v2log2(v2f x) { return (v2f){flog2(x.x), flog2(x.y)}; }

// d_ws derived-constant layout (floats):
//  [0..4]   ewlb  = exp(w_logm)*LOG2E
//  [5..9]   blb   = b_logm*LOG2E
//  [10..14] ewl   = exp(w_logm)
//  [15..19] newtb = -exp(w_ttm)*LOG2E
//  [20..24] nbtb  = -b_ttm*LOG2E
//  [25..29] ewe   = exp(w_exp)
//  [30..34] wte   = exp(w_ttm)*exp(w_exp)
//  [35..39] r1    = sum_j W1[i,j]
//  [40..44] r1b   = r1*LOG2E
//  [45..49] c1b   = (b1 + W1@b_exp)*LOG2E
//  [50..54] r1sq  = r1^2
//  [55..79] W2
//  [80..84] b2b   = b2*LOG2E
//  [85..89] wo
//  [90..94] wob   = wo*LN2
//  [95]     bo
__global__ void setup_kernel(const float* __restrict__ w_logm, const float* __restrict__ b_logm,
                             const float* __restrict__ w_ttm,  const float* __restrict__ b_ttm,
                             const float* __restrict__ w_exp,  const float* __restrict__ b_exp,
                             const float* __restrict__ W1,     const float* __restrict__ b1,
                             const float* __restrict__ W2,     const float* __restrict__ b2,
                             const float* __restrict__ Wo,     const float* __restrict__ bo,
                             float* __restrict__ c)
{
    const int j = threadIdx.x;
    if (j >= J) return;
    const float ewl = __expf(w_logm[j]);
    const float ewt = __expf(w_ttm[j]);
    const float ewe = __expf(w_exp[j]);
    c[0  + j] = ewl * LOG2E;
    c[5  + j] = b_logm[j] * LOG2E;
    c[10 + j] = ewl;
    c[15 + j] = -ewt * LOG2E;
    c[20 + j] = -b_ttm[j] * LOG2E;
    c[25 + j] = ewe;
    c[30 + j] = ewt * ewe;
    float r = 0.0f, cc = b1[j];
#pragma unroll
    for (int t = 0; t < J; ++t) {
        const float w = W1[j * J + t];
        r += w;
        cc = fmaf(w, b_exp[t], cc);
    }
    c[35 + j] = r;
    c[40 + j] = r * LOG2E;
    c[45 + j] = cc * LOG2E;
    c[50 + j] = r * r;
#pragma unroll
    for (int t = 0; t < J; ++t) c[55 + j * J + t] = W2[j * J + t];
    c[80 + j] = b2[j] * LOG2E;
    c[85 + j] = Wo[j];
    c[90 + j] = Wo[j] * LN2;
    if (j == 0) c[95] = bo[0];
}

__global__ __launch_bounds__(256, 6) void smile_main(
    const float* __restrict__ ttm, const float* __restrict__ logm,
    const float* __restrict__ c, float* __restrict__ out, int n)
{
    const int tid = blockIdx.x * blockDim.x + threadIdx.x;
    if (tid * 2 >= n) return;

    const v2f T = ((const v2f*)ttm)[tid];
    const v2f L = ((const v2f*)logm)[tid];

    // ---- uniform loads -> SGPRs ----
    float ewlb[J], blb[J], ewl[J], newtb[J], nbtb[J], ewe[J], wte[J];
#pragma unroll
    for (int j = 0; j < J; ++j) {
        ewlb[j]  = c[0  + j];
        blb[j]   = c[5  + j];
        ewl[j]   = c[10 + j];
        newtb[j] = c[15 + j];
        nbtb[j]  = c[20 + j];
        ewe[j]   = c[25 + j];
        wte[j]   = c[30 + j];
    }

    // ============ phase 1: smile layer + d/dL, d2/dL2, d/dT (2 samples packed) ============
    v2f s = v2s(0.0f), sL = v2s(0.0f), sLL = v2s(0.0f), sT = v2s(0.0f);
#pragma unroll
    for (int j = 0; j < J; ++j) {
        const v2f x2 = vfma(L, ewlb[j], v2s(blb[j]));  // x*log2e
        const v2f ex = v2exp2(x2);                      // e^x
        const v2f x  = x2 * LN2;
        const v2f e2 = ex * ex;
        // merged reciprocal: w1 = 1/(e*e2+1), w2 = 1/(1+ex) via rcp(a*b)
        const v2f a   = vfma(e2, 2.7182818284590452f, 1.0f);
        const v2f b   = ex + 1.0f;
        const v2f rab = v2rcp(a * b);
        const v2f w1  = b * rab;
        const v2f w2  = a * rab;
        const v2f t1  = vfma(w1, -2.0f, 1.0f);          // tanh(x+0.5)
        const v2f t2  = vfma(w2,  2.0f, -1.0f);         // tanh(-x/2)
        const v2f m1  = vfma(-t1, t1, v2s(1.0f));       // sech^2(x+0.5)
        const v2f m2  = vfma(-t2, t2, v2s(1.0f));       // sech^2(x/2)
        const v2f u   = vfma(x, t1, t2 + 5.0e-4f);
        const v2f xm1 = x * m1;
        const v2f ux  = vfma(m2, -0.5f, t1 + xm1);
        const v2f f1  = vfma(-t1, xm1, m1);
        const v2f uxx = vfma(t2 * (-0.5f), m2, f1 + f1);
        const v2f r   = v2rsq(u);                       // u^{-1/2}
        const v2f tl  = u * r;                          // sqrt(u)
        const v2f i2  = r * 0.5f;
        const v2f h   = ux * (r * r);                   // ux/u
        // sigmoid(b_ttm + T*exp(w_ttm))
        const v2f tt  = v2rcp(v2exp2(vfma(T, newtb[j], v2s(nbtb[j]))) + 1.0f);
        const v2f dtt = vfma(-tt, tt, tt);
        const v2f AA   = tt * ewe[j];
        const v2f ewlA = AA * ewl[j];
        s  = vfma(tl, AA, s);
        sL = vfma(ux * i2, ewlA, sL);
        const v2f inner = vfma(ux * (-0.5f), h, uxx);   // uxx - ux^2/(2u)
        sLL = vfma(inner * i2, ewlA * ewl[j], sLL);
        sT  = vfma(tl * dtt, wte[j], sT);
    }

    // ============ phase 2: MLP (log2-domain softplus chain) ============
    float r1[J], r1b[J], c1b[J], r1sq[J], W2r[J * J], b2b[J], wo[J], wob[J];
#pragma unroll
    for (int j = 0; j < J; ++j) {
        r1[j]   = c[35 + j];
        r1b[j]  = c[40 + j];
        c1b[j]  = c[45 + j];
        r1sq[j] = c[50 + j];
        b2b[j]  = c[80 + j];
        wo[j]   = c[85 + j];
        wob[j]  = c[90 + j];
    }
#pragma unroll
    for (int t = 0; t < J * J; ++t) W2r[t] = c[55 + t];
    const float bo0 = c[95];

    // layer 1: a2_i = s*r1b_i + c1b_i (true pre-act * log2e)
    v2f sp2[J], q[J], p[J];
#pragma unroll
    for (int i = 0; i < J; ++i) {
        const v2f a2 = vfma(s, r1b[i], v2s(c1b[i]));
        const v2f ex = v2exp2(a2);                      // e^{a}
        const v2f d  = ex + 1.0f;
        const v2f w  = v2rcp(d);
        const v2f sg = v2s(1.0f) - w;                   // sigmoid
        sp2[i] = v2log2(d);                             // softplus/ln2
        q[i]   = sg * r1[i];
        p[i]   = (w * sg) * r1sq[i];                    // sg' * r1^2
    }

    // layer 2 + head
    v2f o = v2s(bo0), u1 = v2s(0.0f), u2 = v2s(0.0f), u3 = v2s(0.0f);
#pragma unroll
    for (int i = 0; i < J; ++i) {
        v2f g2 = v2s(b2b[i]), Bq = v2s(0.0f), Bp = v2s(0.0f);
#pragma unroll
        for (int j = 0; j < J; ++j) {
            const float w = W2r[i * J + j];
            g2 = vfma(sp2[j], w, g2);
            Bq = vfma(q[j],   w, Bq);
            Bp = vfma(p[j],   w, Bp);
        }
        const v2f ex  = v2exp2(g2);
        const v2f d   = ex + 1.0f;
        const v2f w   = v2rcp(d);
        const v2f sg  = v2s(1.0f) - w;
        const v2f dsg = w * sg;
        o  = vfma(v2log2(d), wob[i], o);                // wo*softplus
        const v2f t = sg * wo[i];
        u1 = vfma(t, Bq, u1);
        u2 = vfma(t, Bp, u2);
        u3 = vfma(dsg * wo[i], Bq * Bq, u3);
    }

    const size_t nn = (size_t)n;
    ((v2f*)(out))[tid]          = o;                             // output
    ((v2f*)(out + nn))[tid]     = sT * u1;                       // grad_ttm1
    ((v2f*)(out + 2 * nn))[tid] = sL * u1;                       // grad_logm1
    ((v2f*)(out + 3 * nn))[tid] = vfma(sL * sL, u3 + u2, sLL * u1); // grad_logm2
}

extern "C" void kernel_launch(void* const* d_in, const int* in_sizes, int n_in,
                              void* d_out, int out_size, void* d_ws, size_t ws_size,
                              hipStream_t stream) {
    const float* ttm    = (const float*)d_in[0];
    const float* logm   = (const float*)d_in[1];
    const float* w_logm = (const float*)d_in[2];
    const float* b_logm = (const float*)d_in[3];
    const float* w_ttm  = (const float*)d_in[4];
    const float* b_ttm  = (const float*)d_in[5];
    const float* w_exp  = (const float*)d_in[6];
    const float* b_exp  = (const float*)d_in[7];
    const float* W1     = (const float*)d_in[8];
    const float* b1     = (const float*)d_in[9];
    const float* W2     = (const float*)d_in[10];
    const float* b2     = (const float*)d_in[11];
    const float* Wo     = (const float*)d_in[12];
    const float* bo     = (const float*)d_in[13];
    float* out = (float*)d_out;
    float* cns = (float*)d_ws;

    const int n = in_sizes[0];
    setup_kernel<<<1, 64, 0, stream>>>(w_logm, b_logm, w_ttm, b_ttm, w_exp, b_exp,
                                       W1, b1, W2, b2, Wo, bo, cns);
    const int threads = (n + 1) / 2;
    const int blocks  = (threads + 255) / 256;
    smile_main<<<blocks, 256, 0, stream>>>(ttm, logm, cns, out, n);
}

// Round 5
// 110.078 us; speedup vs baseline: 1.2267x; 1.0202x over previous
//
#include <hip/hip_runtime.h>
#include <math.h>

#define J 5
#define LOG2E 1.4426950408889634f
#define LN2   0.6931471805599453f

// LUT config: phase-2 is {o, o', o''}(s), cubic Hermite per segment.
#define NSEG   256
#define SMAX   16.0f
#define SEG_STRIDE 20              // floats per segment (12 used, padded to 80 B)
#define LUT_FLOATS (NSEG * SEG_STRIDE)   // 5120
#define CONST_BASE LUT_FLOATS            // phase-1 constants start here

typedef float v2f __attribute__((ext_vector_type(2)));

#if defined(__HIP_DEVICE_COMPILE__) && __has_builtin(__builtin_amdgcn_rcpf)
__device__ __forceinline__ float fastrcp(float x) { return __builtin_amdgcn_rcpf(x); }
#else
__device__ __forceinline__ float fastrcp(float x) { return 1.0f / x; }
#endif

#if defined(__HIP_DEVICE_COMPILE__) && __has_builtin(__builtin_amdgcn_rsqf)
__device__ __forceinline__ float fastrsq(float x) { return __builtin_amdgcn_rsqf(x); }
#else
__device__ __forceinline__ float fastrsq(float x) { return 1.0f / sqrtf(x); }
#endif

#if defined(__HIP_DEVICE_COMPILE__) && __has_builtin(__builtin_amdgcn_exp2f)
__device__ __forceinline__ float fexp2(float x) { return __builtin_amdgcn_exp2f(x); }
#else
__device__ __forceinline__ float fexp2(float x) { return exp2f(x); }
#endif

// ---- packed helpers ----
__device__ __forceinline__ v2f v2s(float a) { return (v2f){a, a}; }
__device__ __forceinline__ v2f vfma(v2f a, v2f b, v2f c) { return __builtin_elementwise_fma(a, b, c); }
__device__ __forceinline__ v2f vfma(v2f a, float b, v2f c) { return __builtin_elementwise_fma(a, v2s(b), c); }
__device__ __forceinline__ v2f v2exp2(v2f x) { return (v2f){fexp2(x.x), fexp2(x.y)}; }
__device__ __forceinline__ v2f v2rcp (v2f x) { return (v2f){fastrcp(x.x), fastrcp(x.y)}; }
__device__ __forceinline__ v2f v2rsq (v2f x) { return (v2f){fastrsq(x.x), fastrsq(x.y)}; }

// ---------------- setup: build phase-1 constants + phase-2 Hermite LUT ----------------
// Node eval: o, o', o'', o''' of the MLP head as functions of s (true domain).
__device__ void node_eval(float s, const float* r1, const float* c1,
                          const float* W2, const float* b2, const float* wo, float bo,
                          float& o, float& o1, float& o2, float& o3)
{
    float h[J], h1[J], h2[J], h3[J];
#pragma unroll
    for (int j = 0; j < J; ++j) {
        const float a  = fmaf(r1[j], s, c1[j]);
        const float e  = __expf(-fabsf(a));
        const float w  = fastrcp(1.0f + e);
        const float sg = (a >= 0.0f) ? w : 1.0f - w;
        const float sp = fmaxf(a, 0.0f) + __logf(1.0f + e);
        const float d1 = sg * (1.0f - sg);
        const float d2 = d1 * (1.0f - 2.0f * sg);
        const float r  = r1[j];
        h[j]  = sp;
        h1[j] = sg * r;
        h2[j] = d1 * r * r;
        h3[j] = d2 * r * r * r;
    }
    o = bo; o1 = 0.0f; o2 = 0.0f; o3 = 0.0f;
#pragma unroll
    for (int i = 0; i < J; ++i) {
        float g = b2[i], G1 = 0.0f, G2 = 0.0f, G3 = 0.0f;
#pragma unroll
        for (int j = 0; j < J; ++j) {
            const float w = W2[i * J + j];
            g  = fmaf(w, h[j],  g);
            G1 = fmaf(w, h1[j], G1);
            G2 = fmaf(w, h2[j], G2);
            G3 = fmaf(w, h3[j], G3);
        }
        const float e  = __expf(-fabsf(g));
        const float w  = fastrcp(1.0f + e);
        const float sg = (g >= 0.0f) ? w : 1.0f - w;
        const float sp = fmaxf(g, 0.0f) + __logf(1.0f + e);
        const float d1 = sg * (1.0f - sg);
        const float d2 = d1 * (1.0f - 2.0f * sg);
        o  = fmaf(wo[i], sp, o);
        o1 = fmaf(wo[i], sg * G1, o1);
        o2 = fmaf(wo[i], fmaf(d1, G1 * G1, sg * G2), o2);
        o3 = fmaf(wo[i], fmaf(d2 * G1, G1 * G1, fmaf(3.0f * d1, G1 * G2, sg * G3)), o3);
    }
}

__global__ void setup_kernel(const float* __restrict__ w_logm, const float* __restrict__ b_logm,
                             const float* __restrict__ w_ttm,  const float* __restrict__ b_ttm,
                             const float* __restrict__ w_exp,  const float* __restrict__ b_exp,
                             const float* __restrict__ W1,     const float* __restrict__ b1,
                             const float* __restrict__ W2,     const float* __restrict__ b2,
                             const float* __restrict__ Wo,     const float* __restrict__ bo,
                             float* __restrict__ c)
{
    const int k = threadIdx.x;           // 0..255, one per LUT segment

    // ---- phase-1 constants (threads 0..4) ----
    if (k < J) {
        const float ewl = __expf(w_logm[k]);
        const float ewt = __expf(w_ttm[k]);
        const float ewe = __expf(w_exp[k]);
        c[CONST_BASE + 0  + k] = ewl * LOG2E;
        c[CONST_BASE + 5  + k] = b_logm[k] * LOG2E;
        c[CONST_BASE + 10 + k] = ewl;
        c[CONST_BASE + 15 + k] = -ewt * LOG2E;
        c[CONST_BASE + 20 + k] = -b_ttm[k] * LOG2E;
        c[CONST_BASE + 25 + k] = ewe;
        c[CONST_BASE + 30 + k] = ewt * ewe;
    }

    // ---- MLP params (every thread loads its own copy; tiny + L2 cached) ----
    float r1[J], c1[J], b2r[J], wor[J], W2r[J * J];
#pragma unroll
    for (int i = 0; i < J; ++i) {
        float r = 0.0f, cc = b1[i];
#pragma unroll
        for (int j = 0; j < J; ++j) {
            const float w = W1[i * J + j];
            r += w;
            cc = fmaf(w, b_exp[j], cc);
        }
        r1[i] = r; c1[i] = cc;
        b2r[i] = b2[i]; wor[i] = Wo[i];
    }
#pragma unroll
    for (int t = 0; t < J * J; ++t) W2r[t] = W2[t];
    const float bo0 = bo[0];

    // ---- Hermite cubic coefficients for segment k ----
    const float h  = SMAX / (float)NSEG;
    const float s0 = h * (float)k;
    float Fa0, Fa1, Fa2, Fa3, Fb0, Fb1, Fb2, Fb3;
    node_eval(s0,     r1, c1, W2r, b2r, wor, bo0, Fa0, Fa1, Fa2, Fa3);
    node_eval(s0 + h, r1, c1, W2r, b2r, wor, bo0, Fb0, Fb1, Fb2, Fb3);

    float* seg = c + k * SEG_STRIDE;
    // F0 = o   (value o, slope o');  F1 = o' (slope o''); F2 = o'' (slope o''')
    // monomial in t = (s-s0)/h:  c0 + t(c1 + t(c2 + t c3))
    {   // F0
        const float Da = h * Fa1, Db = h * Fb1, D = Fb0 - Fa0;
        seg[0] = Fa0; seg[1] = Da;
        seg[2] = 3.0f * D - 2.0f * Da - Db;
        seg[3] = -2.0f * D + Da + Db;
    }
    {   // F1
        const float Da = h * Fa2, Db = h * Fb2, D = Fb1 - Fa1;
        seg[4] = Fa1; seg[5] = Da;
        seg[6] = 3.0f * D - 2.0f * Da - Db;
        seg[7] = -2.0f * D + Da + Db;
    }
    {   // F2
        const float Da = h * Fa3, Db = h * Fb3, D = Fb2 - Fa2;
        seg[8]  = Fa2; seg[9]  = Da;
        seg[10] = 3.0f * D - 2.0f * Da - Db;
        seg[11] = -2.0f * D + Da + Db;
    }
    seg[12] = 0.0f; seg[13] = 0.0f; seg[14] = 0.0f; seg[15] = 0.0f;
    seg[16] = 0.0f; seg[17] = 0.0f; seg[18] = 0.0f; seg[19] = 0.0f;
}

// ---------------- main kernel ----------------
__device__ __forceinline__ void lut_eval(const float* __restrict__ lut, float s,
                                         float& F0, float& F1, float& F2)
{
    float t = s * ((float)NSEG / SMAX);
    t = fminf(fmaxf(t, 0.0f), (float)NSEG - 0.0005f);   // v_med3
    const float fl = floorf(t);
    const float fr = t - fl;
    const float* cp = lut + (int)fl * SEG_STRIDE;
    const float4 A = *(const float4*)(cp);
    const float4 Bq = *(const float4*)(cp + 4);
    const float4 C = *(const float4*)(cp + 8);
    F0 = fmaf(fmaf(fmaf(A.w, fr, A.z), fr, A.y), fr, A.x);
    F1 = fmaf(fmaf(fmaf(Bq.w, fr, Bq.z), fr, Bq.y), fr, Bq.x);
    F2 = fmaf(fmaf(fmaf(C.w, fr, C.z), fr, C.y), fr, C.x);
}

__global__ __launch_bounds__(256, 6) void smile_main(
    const float* __restrict__ ttm, const float* __restrict__ logm,
    const float* __restrict__ c, float* __restrict__ out, int n)
{
    __shared__ __align__(16) float lut[LUT_FLOATS];
    // cooperative fill: 5120 floats = 1280 float4, coalesced, L2/LLC-hot
    for (int t = threadIdx.x; t < LUT_FLOATS / 4; t += 256)
        ((float4*)lut)[t] = ((const float4*)c)[t];
    __syncthreads();

    const int tid = blockIdx.x * blockDim.x + threadIdx.x;
    if (tid * 2 >= n) return;

    const v2f T = ((const v2f*)ttm)[tid];
    const v2f L = ((const v2f*)logm)[tid];

    // ---- phase-1 constants (uniform -> SGPRs) ----
    const float* cb = c + CONST_BASE;
    float ewlb[J], blb[J], ewl[J], newtb[J], nbtb[J], ewe[J], wte[J];
#pragma unroll
    for (int j = 0; j < J; ++j) {
        ewlb[j]  = cb[0  + j];
        blb[j]   = cb[5  + j];
        ewl[j]   = cb[10 + j];
        newtb[j] = cb[15 + j];
        nbtb[j]  = cb[20 + j];
        ewe[j]   = cb[25 + j];
        wte[j]   = cb[30 + j];
    }

    // ============ phase 1: smile layer + d/dL, d2/dL2, d/dT (2 samples packed) ============
    v2f s = v2s(0.0f), sL = v2s(0.0f), sLL = v2s(0.0f), sT = v2s(0.0f);
#pragma unroll
    for (int j = 0; j < J; ++j) {
        const v2f x2 = vfma(L, ewlb[j], v2s(blb[j]));  // x*log2e
        const v2f ex = v2exp2(x2);                      // e^x
        const v2f x  = x2 * LN2;
        const v2f e2 = ex * ex;
        const v2f a   = vfma(e2, 2.7182818284590452f, v2s(1.0f));
        const v2f b   = ex + 1.0f;
        const v2f rab = v2rcp(a * b);
        const v2f w1  = b * rab;
        const v2f w2  = a * rab;
        const v2f t1  = vfma(w1, -2.0f, v2s(1.0f));     // tanh(x+0.5)
        const v2f t2  = vfma(w2,  2.0f, v2s(-1.0f));    // tanh(-x/2)
        const v2f m1  = vfma(-t1, t1, v2s(1.0f));
        const v2f m2  = vfma(-t2, t2, v2s(1.0f));
        const v2f u   = vfma(x, t1, t2 + 5.0e-4f);
        const v2f xm1 = x * m1;
        const v2f ux  = vfma(m2, -0.5f, t1 + xm1);
        const v2f f1  = vfma(-t1, xm1, m1);
        const v2f uxx = vfma(t2 * (-0.5f), m2, f1 + f1);
        const v2f r   = v2rsq(u);
        const v2f tl  = u * r;                          // sqrt(u)
        const v2f i2  = r * 0.5f;
        const v2f hh  = ux * (r * r);                   // ux/u
        const v2f tt  = v2rcp(v2exp2(vfma(T, newtb[j], v2s(nbtb[j]))) + 1.0f);
        const v2f dtt = vfma(-tt, tt, tt);
        const v2f AA   = tt * ewe[j];
        const v2f ewlA = AA * ewl[j];
        s  = vfma(tl, AA, s);
        sL = vfma(ux * i2, ewlA, sL);
        const v2f inner = vfma(ux * (-0.5f), hh, uxx);
        sLL = vfma(inner * i2, ewlA * ewl[j], sLL);
        sT  = vfma(tl * dtt, wte[j], sT);
    }

    // ============ phase 2: LUT eval of {o, o', o''}(s) ============
    float F0x, F1x, F2x, F0y, F1y, F2y;
    lut_eval(lut, s.x, F0x, F1x, F2x);
    lut_eval(lut, s.y, F0y, F1y, F2y);
    const v2f F0 = (v2f){F0x, F0y};
    const v2f F1 = (v2f){F1x, F1y};
    const v2f F2 = (v2f){F2x, F2y};

    const size_t nn = (size_t)n;
    ((v2f*)(out))[tid]          = F0;                          // output
    ((v2f*)(out + nn))[tid]     = sT * F1;                     // grad_ttm1
    ((v2f*)(out + 2 * nn))[tid] = sL * F1;                     // grad_logm1
    ((v2f*)(out + 3 * nn))[tid] = vfma(sL * sL, F2, sLL * F1); // grad_logm2
}

extern "C" void kernel_launch(void* const* d_in, const int* in_sizes, int n_in,
                              void* d_out, int out_size, void* d_ws, size_t ws_size,
                              hipStream_t stream) {
    const float* ttm    = (const float*)d_in[0];
    const float* logm   = (const float*)d_in[1];
    const float* w_logm = (const float*)d_in[2];
    const float* b_logm = (const float*)d_in[3];
    const float* w_ttm  = (const float*)d_in[4];
    const float* b_ttm  = (const float*)d_in[5];
    const float* w_exp  = (const float*)d_in[6];
    const float* b_exp  = (const float*)d_in[7];
    const float* W1     = (const float*)d_in[8];
    const float* b1     = (const float*)d_in[9];
    const float* W2     = (const float*)d_in[10];
    const float* b2     = (const float*)d_in[11];
    const float* Wo     = (const float*)d_in[12];
    const float* bo     = (const float*)d_in[13];
    float* out = (float*)d_out;
    float* cns = (float*)d_ws;   // LUT_FLOATS + 35 floats ≈ 20.6 KB

    const int n = in_sizes[0];
    setup_kernel<<<1, NSEG, 0, stream>>>(w_logm, b_logm, w_ttm, b_ttm, w_exp, b_exp,
                                         W1, b1, W2, b2, Wo, bo, cns);
    const int threads = (n + 1) / 2;
    const int blocks  = (threads + 255) / 256;
    smile_main<<<blocks, 256, 0, stream>>>(ttm, logm, cns, out, n);
}

// Round 7
// 107.596 us; speedup vs baseline: 1.2550x; 1.0231x over previous
//
#include <hip/hip_runtime.h>
#include <math.h>

#define J 5
#define LOG2E 1.4426950408889634f
#define LN2   0.6931471805599453f

// LUT config: phase-2 is {o, o', o''}(s), cubic Hermite per segment.
#define NSEG   128
#define SMAX   16.0f
#define SEG_STRIDE 12                    // floats per segment (3 x float4)
#define LUT_FLOATS (NSEG * SEG_STRIDE)   // 1536 floats = 6 KB
#define CONST_BASE LUT_FLOATS            // phase-1 constants start here

typedef float v2f __attribute__((ext_vector_type(2)));

#if defined(__HIP_DEVICE_COMPILE__) && __has_builtin(__builtin_amdgcn_rcpf)
__device__ __forceinline__ float fastrcp(float x) { return __builtin_amdgcn_rcpf(x); }
#else
__device__ __forceinline__ float fastrcp(float x) { return 1.0f / x; }
#endif

#if defined(__HIP_DEVICE_COMPILE__) && __has_builtin(__builtin_amdgcn_rsqf)
__device__ __forceinline__ float fastrsq(float x) { return __builtin_amdgcn_rsqf(x); }
#else
__device__ __forceinline__ float fastrsq(float x) { return 1.0f / sqrtf(x); }
#endif

#if defined(__HIP_DEVICE_COMPILE__) && __has_builtin(__builtin_amdgcn_exp2f)
__device__ __forceinline__ float fexp2(float x) { return __builtin_amdgcn_exp2f(x); }
#else
__device__ __forceinline__ float fexp2(float x) { return exp2f(x); }
#endif

// ---- packed helpers ----
__device__ __forceinline__ v2f v2s(float a) { return (v2f){a, a}; }
__device__ __forceinline__ v2f vfma(v2f a, v2f b, v2f c) { return __builtin_elementwise_fma(a, b, c); }
__device__ __forceinline__ v2f vfma(v2f a, float b, v2f c) { return __builtin_elementwise_fma(a, v2s(b), c); }
__device__ __forceinline__ v2f v2exp2(v2f x) { return (v2f){fexp2(x.x), fexp2(x.y)}; }
__device__ __forceinline__ v2f v2rcp (v2f x) { return (v2f){fastrcp(x.x), fastrcp(x.y)}; }
__device__ __forceinline__ v2f v2rsq (v2f x) { return (v2f){fastrsq(x.x), fastrsq(x.y)}; }

// ---------------- setup: build phase-1 constants + phase-2 Hermite LUT ----------------
__device__ void node_eval(float s, const float* r1, const float* c1,
                          const float* W2, const float* b2, const float* wo, float bo,
                          float& o, float& o1, float& o2, float& o3)
{
    float h[J], h1[J], h2[J], h3[J];
#pragma unroll
    for (int j = 0; j < J; ++j) {
        const float a  = fmaf(r1[j], s, c1[j]);
        const float e  = __expf(-fabsf(a));
        const float w  = fastrcp(1.0f + e);
        const float sg = (a >= 0.0f) ? w : 1.0f - w;
        const float sp = fmaxf(a, 0.0f) + __logf(1.0f + e);
        const float d1 = sg * (1.0f - sg);
        const float d2 = d1 * (1.0f - 2.0f * sg);
        const float r  = r1[j];
        h[j]  = sp;
        h1[j] = sg * r;
        h2[j] = d1 * r * r;
        h3[j] = d2 * r * r * r;
    }
    o = bo; o1 = 0.0f; o2 = 0.0f; o3 = 0.0f;
#pragma unroll
    for (int i = 0; i < J; ++i) {
        float g = b2[i], G1 = 0.0f, G2 = 0.0f, G3 = 0.0f;
#pragma unroll
        for (int j = 0; j < J; ++j) {
            const float w = W2[i * J + j];
            g  = fmaf(w, h[j],  g);
            G1 = fmaf(w, h1[j], G1);
            G2 = fmaf(w, h2[j], G2);
            G3 = fmaf(w, h3[j], G3);
        }
        const float e  = __expf(-fabsf(g));
        const float w  = fastrcp(1.0f + e);
        const float sg = (g >= 0.0f) ? w : 1.0f - w;
        const float sp = fmaxf(g, 0.0f) + __logf(1.0f + e);
        const float d1 = sg * (1.0f - sg);
        const float d2 = d1 * (1.0f - 2.0f * sg);
        o  = fmaf(wo[i], sp, o);
        o1 = fmaf(wo[i], sg * G1, o1);
        o2 = fmaf(wo[i], fmaf(d1, G1 * G1, sg * G2), o2);
        o3 = fmaf(wo[i], fmaf(d2 * G1, G1 * G1, fmaf(3.0f * d1, G1 * G2, sg * G3)), o3);
    }
}

__global__ void setup_kernel(const float* __restrict__ w_logm, const float* __restrict__ b_logm,
                             const float* __restrict__ w_ttm,  const float* __restrict__ b_ttm,
                             const float* __restrict__ w_exp,  const float* __restrict__ b_exp,
                             const float* __restrict__ W1,     const float* __restrict__ b1,
                             const float* __restrict__ W2,     const float* __restrict__ b2,
                             const float* __restrict__ Wo,     const float* __restrict__ bo,
                             float* __restrict__ c)
{
    const int k = threadIdx.x;           // 0..NSEG-1, one per LUT segment

    if (k < J) {
        const float ewl = __expf(w_logm[k]);
        const float ewt = __expf(w_ttm[k]);
        const float ewe = __expf(w_exp[k]);
        c[CONST_BASE + 0  + k] = ewl * LOG2E;
        c[CONST_BASE + 5  + k] = b_logm[k] * LOG2E;
        c[CONST_BASE + 10 + k] = ewl;
        c[CONST_BASE + 15 + k] = -ewt * LOG2E;
        c[CONST_BASE + 20 + k] = -b_ttm[k] * LOG2E;
        c[CONST_BASE + 25 + k] = ewe;
        c[CONST_BASE + 30 + k] = ewt * ewe;
    }

    float r1[J], c1[J], b2r[J], wor[J], W2r[J * J];
#pragma unroll
    for (int i = 0; i < J; ++i) {
        float r = 0.0f, cc = b1[i];
#pragma unroll
        for (int j = 0; j < J; ++j) {
            const float w = W1[i * J + j];
            r += w;
            cc = fmaf(w, b_exp[j], cc);
        }
        r1[i] = r; c1[i] = cc;
        b2r[i] = b2[i]; wor[i] = Wo[i];
    }
#pragma unroll
    for (int t = 0; t < J * J; ++t) W2r[t] = W2[t];
    const float bo0 = bo[0];

    const float h  = SMAX / (float)NSEG;
    const float s0 = h * (float)k;
    float Fa0, Fa1, Fa2, Fa3, Fb0, Fb1, Fb2, Fb3;
    node_eval(s0,     r1, c1, W2r, b2r, wor, bo0, Fa0, Fa1, Fa2, Fa3);
    node_eval(s0 + h, r1, c1, W2r, b2r, wor, bo0, Fb0, Fb1, Fb2, Fb3);

    float* seg = c + k * SEG_STRIDE;
    {   // F0 = o
        const float Da = h * Fa1, Db = h * Fb1, D = Fb0 - Fa0;
        seg[0] = Fa0; seg[1] = Da;
        seg[2] = 3.0f * D - 2.0f * Da - Db;
        seg[3] = -2.0f * D + Da + Db;
    }
    {   // F1 = o'
        const float Da = h * Fa2, Db = h * Fb2, D = Fb1 - Fa1;
        seg[4] = Fa1; seg[5] = Da;
        seg[6] = 3.0f * D - 2.0f * Da - Db;
        seg[7] = -2.0f * D + Da + Db;
    }
    {   // F2 = o''
        const float Da = h * Fa3, Db = h * Fb3, D = Fb2 - Fa2;
        seg[8]  = Fa2; seg[9]  = Da;
        seg[10] = 3.0f * D - 2.0f * Da - Db;
        seg[11] = -2.0f * D + Da + Db;
    }
}

// ---------------- main kernel ----------------
struct P1Consts {
    float ewlb[J], blb[J], ewl[J], newtb[J], nbtb[J], ewe[J], wte[J];
};

__device__ __forceinline__ void phase1(v2f T, v2f L, const P1Consts& K,
                                       v2f& s, v2f& sL, v2f& sLL, v2f& sT)
{
    s = v2s(0.0f); sL = v2s(0.0f); sLL = v2s(0.0f); sT = v2s(0.0f);
#pragma unroll
    for (int j = 0; j < J; ++j) {
        const v2f x2 = vfma(L, K.ewlb[j], v2s(K.blb[j]));  // x*log2e
        const v2f ex = v2exp2(x2);                          // e^x
        const v2f x  = x2 * LN2;
        const v2f e2 = ex * ex;
        const v2f a   = vfma(e2, 2.7182818284590452f, v2s(1.0f));
        const v2f b   = ex + 1.0f;
        const v2f rab = v2rcp(a * b);
        const v2f w1  = b * rab;
        const v2f w2  = a * rab;
        const v2f t1  = vfma(w1, -2.0f, v2s(1.0f));     // tanh(x+0.5)
        const v2f t2  = vfma(w2,  2.0f, v2s(-1.0f));    // tanh(-x/2)
        const v2f m1  = vfma(-t1, t1, v2s(1.0f));
        const v2f m2  = vfma(-t2, t2, v2s(1.0f));
        const v2f u   = vfma(x, t1, t2 + 5.0e-4f);
        const v2f xm1 = x * m1;
        const v2f ux  = vfma(m2, -0.5f, t1 + xm1);
        const v2f f1  = vfma(-t1, xm1, m1);
        const v2f uxx = vfma(t2 * (-0.5f), m2, f1 + f1);
        const v2f r   = v2rsq(u);
        const v2f tl  = u * r;                          // sqrt(u)
        const v2f i2  = r * 0.5f;
        const v2f hh  = ux * (r * r);                   // ux/u
        const v2f tt  = v2rcp(v2exp2(vfma(T, K.newtb[j], v2s(K.nbtb[j]))) + 1.0f);
        const v2f dtt = vfma(-tt, tt, tt);
        const v2f AA   = tt * K.ewe[j];
        const v2f ewlA = AA * K.ewl[j];
        s  = vfma(tl, AA, s);
        sL = vfma(ux * i2, ewlA, sL);
        const v2f inner = vfma(ux * (-0.5f), hh, uxx);
        sLL = vfma(inner * i2, ewlA * K.ewl[j], sLL);
        sT  = vfma(tl * dtt, K.wte[j], sT);
    }
}

__device__ __forceinline__ void lut_eval(const float* __restrict__ lut, float s,
                                         float& F0, float& F1, float& F2)
{
    float t = s * ((float)NSEG / SMAX);
    t = fminf(fmaxf(t, 0.0f), (float)NSEG - 0.0005f);   // v_med3
    const float fl = floorf(t);
    const float fr = t - fl;
    const float* cp = lut + (int)fl * SEG_STRIDE;
    const float4 A = *(const float4*)(cp);
    const float4 B = *(const float4*)(cp + 4);
    const float4 C = *(const float4*)(cp + 8);
    F0 = fmaf(fmaf(fmaf(A.w, fr, A.z), fr, A.y), fr, A.x);
    F1 = fmaf(fmaf(fmaf(B.w, fr, B.z), fr, B.y), fr, B.x);
    F2 = fmaf(fmaf(fmaf(C.w, fr, C.z), fr, C.y), fr, C.x);
}

__global__ __launch_bounds__(256, 4) void smile_main(
    const float* __restrict__ ttm, const float* __restrict__ logm,
    const float* __restrict__ c, float* __restrict__ out, int n)
{
    __shared__ __align__(16) float lut[LUT_FLOATS];
    // cooperative fill: 1536 floats = 384 float4
    for (int t = threadIdx.x; t < LUT_FLOATS / 4; t += 256)
        ((float4*)lut)[t] = ((const float4*)c)[t];
    __syncthreads();

    const int tid = blockIdx.x * blockDim.x + threadIdx.x;
    if (tid * 4 >= n) return;

    // 4 samples/thread as two packed pairs
    const float4 T4 = ((const float4*)ttm)[tid];
    const float4 L4 = ((const float4*)logm)[tid];
    const v2f Ta = (v2f){T4.x, T4.y}, Tb = (v2f){T4.z, T4.w};
    const v2f La = (v2f){L4.x, L4.y}, Lb = (v2f){L4.z, L4.w};

    // ---- phase-1 constants (uniform -> SGPRs) ----
    P1Consts K;
    const float* cb = c + CONST_BASE;
#pragma unroll
    for (int j = 0; j < J; ++j) {
        K.ewlb[j]  = cb[0  + j];
        K.blb[j]   = cb[5  + j];
        K.ewl[j]   = cb[10 + j];
        K.newtb[j] = cb[15 + j];
        K.nbtb[j]  = cb[20 + j];
        K.ewe[j]   = cb[25 + j];
        K.wte[j]   = cb[30 + j];
    }

    v2f sa, sLa, sLLa, sTa, sb, sLb, sLLb, sTb;
    phase1(Ta, La, K, sa, sLa, sLLa, sTa);
    phase1(Tb, Lb, K, sb, sLb, sLLb, sTb);

    // ---- phase 2: LUT eval of {o, o', o''}(s) for 4 samples ----
    float F0[4], F1[4], F2[4];
    lut_eval(lut, sa.x, F0[0], F1[0], F2[0]);
    lut_eval(lut, sa.y, F0[1], F1[1], F2[1]);
    lut_eval(lut, sb.x, F0[2], F1[2], F2[2]);
    lut_eval(lut, sb.y, F0[3], F1[3], F2[3]);

    const size_t nn = (size_t)n;
    ((float4*)(out))[tid] = make_float4(F0[0], F0[1], F0[2], F0[3]);
    ((float4*)(out + nn))[tid] =
        make_float4(sTa.x * F1[0], sTa.y * F1[1], sTb.x * F1[2], sTb.y * F1[3]);
    ((float4*)(out + 2 * nn))[tid] =
        make_float4(sLa.x * F1[0], sLa.y * F1[1], sLb.x * F1[2], sLb.y * F1[3]);
    ((float4*)(out + 3 * nn))[tid] = make_float4(
        fmaf(sLa.x * sLa.x, F2[0], sLLa.x * F1[0]),
        fmaf(sLa.y * sLa.y, F2[1], sLLa.y * F1[1]),
        fmaf(sLb.x * sLb.x, F2[2], sLLb.x * F1[2]),
        fmaf(sLb.y * sLb.y, F2[3], sLLb.y * F1[3]));
}

extern "C" void kernel_launch(void* const* d_in, const int* in_sizes, int n_in,
                              void* d_out, int out_size, void* d_ws, size_t ws_size,
                              hipStream_t stream) {
    const float* ttm    = (const float*)d_in[0];
    const float* logm   = (const float*)d_in[1];
    const float* w_logm = (const float*)d_in[2];
    const float* b_logm = (const float*)d_in[3];
    const float* w_ttm  = (const float*)d_in[4];
    const float* b_ttm  = (const float*)d_in[5];
    const float* w_exp  = (const float*)d_in[6];
    const float* b_exp  = (const float*)d_in[7];
    const float* W1     = (const float*)d_in[8];
    const float* b1     = (const float*)d_in[9];
    const float* W2     = (const float*)d_in[10];
    const float* b2     = (const float*)d_in[11];
    const float* Wo     = (const float*)d_in[12];
    const float* bo     = (const float*)d_in[13];
    float* out = (float*)d_out;
    float* cns = (float*)d_ws;   // 1536 + 35 floats ≈ 6.3 KB

    const int n = in_sizes[0];
    setup_kernel<<<1, NSEG, 0, stream>>>(w_logm, b_logm, w_ttm, b_ttm, w_exp, b_exp,
                                         W1, b1, W2, b2, Wo, bo, cns);
    const int threads = (n + 3) / 4;
    const int blocks  = (threads + 255) / 256;
    smile_main<<<blocks, 256, 0, stream>>>(ttm, logm, cns, out, n);
}